// Round 5
// baseline (224.481 us; speedup 1.0000x reference)
//
#include <hip/hip_runtime.h>

#define DIM 256

// SWEEP layout: wave w (of NW=8192) handles rows {w + NW*i}, i=0..127.
// At sweep-step i, the whole chip writes the contiguous 8 MiB band of rows
// [NW*i, NW*(i+1)) and marches forward — mimics fillBufferAligned's pattern
// (6.6 TB/s) for HBM row-buffer/page locality, vs round-2's 8192 scattered
// 64 KiB streams (5.6 TB/s).
// x for wave w is stride-NW: fetched via two 64-lane gathers (lane l ->
// x[w + NW*l]); adjacent waves share cache lines so HBM fetch stays ~4 MB.
// Per row: broadcast via __shfl, 2 muls, 2 fracts, 4 HW transcendentals
// (v_sin/v_cos take REVOLUTIONS -> premultiply freqs by 1/(2pi)), one
// float4 store (wave = 1 KiB contiguous).
__global__ __launch_bounds__(256) void SinusoidalEmbedding_kernel(
    const float* __restrict__ x, float* __restrict__ out, int n) {
    const int lane = threadIdx.x & 63;
    const int wid = blockIdx.x * (blockDim.x >> 6) + (threadIdx.x >> 6);
    const int nw = gridDim.x * (blockDim.x >> 6);  // 8192 waves

    const float k = 0.103810252965228506f;      // log2(10000)/128
    const float INV2PI = 0.15915494309189535f;  // radians -> revolutions
    const float i0f = (float)(2 * lane);
    const float g0 = exp2f(-i0f * k) * INV2PI;          // lane's freq 2j
    const float g1 = exp2f(-(i0f + 1.0f) * k) * INV2PI; // lane's freq 2j+1

    for (long ib = 0; wid + ib * (long)nw < n; ib += 128) {
        // Gather this batch's 128 timesteps (2 loads, lane l -> step ib+l).
        const long rg0 = wid + (ib + lane) * (long)nw;
        const long rg1 = wid + (ib + 64 + lane) * (long)nw;
        const float xg0 = (rg0 < n) ? x[rg0] : 0.0f;
        const float xg1 = (rg1 < n) ? x[rg1] : 0.0f;
        const bool full = (wid + (ib + 127) * (long)nw) < n;

        if (full) {
            float* o = out + (size_t)(wid + ib * (size_t)nw) * DIM + lane * 4;
            const size_t stride = (size_t)nw * DIM;  // 8 MiB per sweep step
            #pragma unroll 8
            for (int i = 0; i < 64; ++i) {
                const float xr = __shfl(xg0, i);
                float t0 = xr * g0; t0 -= floorf(t0);  // v_fract
                float t1 = xr * g1; t1 -= floorf(t1);
                float4 v;
                v.x = __builtin_amdgcn_sinf(t0);  // sin(2*pi*t)
                v.y = __builtin_amdgcn_cosf(t0);
                v.z = __builtin_amdgcn_sinf(t1);
                v.w = __builtin_amdgcn_cosf(t1);
                *reinterpret_cast<float4*>(o + (size_t)i * stride) = v;
            }
            float* o2 = o + 64 * stride;
            #pragma unroll 8
            for (int i = 0; i < 64; ++i) {
                const float xr = __shfl(xg1, i);
                float t0 = xr * g0; t0 -= floorf(t0);
                float t1 = xr * g1; t1 -= floorf(t1);
                float4 v;
                v.x = __builtin_amdgcn_sinf(t0);
                v.y = __builtin_amdgcn_cosf(t0);
                v.z = __builtin_amdgcn_sinf(t1);
                v.w = __builtin_amdgcn_cosf(t1);
                *reinterpret_cast<float4*>(o2 + (size_t)i * stride) = v;
            }
        } else {
            for (int i = 0; i < 128; ++i) {  // guarded tail — not hit at n=1M
                const long row = wid + (ib + i) * (long)nw;
                if (row >= n) break;
                const float xr = (i < 64) ? __shfl(xg0, i & 63) : __shfl(xg1, i & 63);
                float t0 = xr * g0; t0 -= floorf(t0);
                float t1 = xr * g1; t1 -= floorf(t1);
                float4 v;
                v.x = __builtin_amdgcn_sinf(t0);
                v.y = __builtin_amdgcn_cosf(t0);
                v.z = __builtin_amdgcn_sinf(t1);
                v.w = __builtin_amdgcn_cosf(t1);
                *reinterpret_cast<float4*>(out + (size_t)row * DIM + lane * 4) = v;
            }
        }
    }
}

extern "C" void kernel_launch(void* const* d_in, const int* in_sizes, int n_in,
                              void* d_out, int out_size, void* d_ws, size_t ws_size,
                              hipStream_t stream) {
    const float* x = (const float*)d_in[0];
    float* out = (float*)d_out;
    const int n = in_sizes[0];  // 1048576 rows

    const int block = 256;  // 4 waves/block
    const int grid = 2048;  // 8192 waves; 128 sweep-steps each at n=1M
    SinusoidalEmbedding_kernel<<<grid, block, 0, stream>>>(x, out, n);
}

// Round 6
// 204.733 us; speedup vs baseline: 1.0965x; 1.0965x over previous
//
#include <hip/hip_runtime.h>

#define DIM 256

// fill-shaped dispatch: 256 blocks x 256 thr = 1024 waves (~1 block/CU, ~11%
// occupancy — same shape as the 6.6 TB/s fillBufferAligned). Each wave owns a
// CONTIGUOUS 1 MiB slab (1024 rows): 16 batches of {1 coalesced x-load -> 64
// fully-unrolled rows}. Full unroll => __shfl(xv, const) compiles to
// v_readlane (SGPR broadcast). Hypothesis under test: fewer, longer write
// streams (1024 vs 8192) => better HBM page locality / write-combining.
// v_sin/v_cos take REVOLUTIONS: freqs premultiplied by 1/(2pi), v_fract reduce.
__global__ __launch_bounds__(256) void SinusoidalEmbedding_kernel(
    const float* __restrict__ x, float* __restrict__ out, int n) {
    const int lane = threadIdx.x & 63;
    const int wid = blockIdx.x * (blockDim.x >> 6) + (threadIdx.x >> 6);
    const int nw = gridDim.x * (blockDim.x >> 6);  // 1024 waves

    const float k = 0.103810252965228506f;      // log2(10000)/128
    const float INV2PI = 0.15915494309189535f;  // radians -> revolutions
    const float i0f = (float)(2 * lane);
    const float g0 = exp2f(-i0f * k) * INV2PI;          // lane's freq 2j
    const float g1 = exp2f(-(i0f + 1.0f) * k) * INV2PI; // lane's freq 2j+1

    // Contiguous batch assignment: B full 64-row batches split K(+1) per wave.
    const int B = n >> 6;
    const int K = B / nw;
    const int R = B % nw;
    const int myK = K + (wid < R ? 1 : 0);
    const int first = wid * K + (wid < R ? wid : R);

    for (int b = 0; b < myK; ++b) {
        const int base = (first + b) << 6;
        const float xv = x[base + lane];  // 64 rows' timesteps, 1 coalesced load
        float* o = out + (size_t)base * DIM + lane * 4;
        #pragma unroll
        for (int r = 0; r < 64; ++r) {
            const float xr = __shfl(xv, r);  // v_readlane (const idx, full unroll)
            const float t0 = __builtin_amdgcn_fractf(xr * g0);
            const float t1 = __builtin_amdgcn_fractf(xr * g1);
            float4 v;
            v.x = __builtin_amdgcn_sinf(t0);  // sin(2*pi*t)
            v.y = __builtin_amdgcn_cosf(t0);
            v.z = __builtin_amdgcn_sinf(t1);
            v.w = __builtin_amdgcn_cosf(t1);
            *reinterpret_cast<float4*>(o + (size_t)r * DIM) = v;
        }
    }

    // Tail rows (n % 64) — wave 0 only; not hit at n = 1048576.
    const int tail = n & 63;
    if (tail && wid == 0) {
        const int base = B << 6;
        const float xv = (lane < tail) ? x[base + lane] : 0.0f;
        for (int r = 0; r < tail; ++r) {
            const float xr = __shfl(xv, r);
            const float t0 = __builtin_amdgcn_fractf(xr * g0);
            const float t1 = __builtin_amdgcn_fractf(xr * g1);
            float4 v;
            v.x = __builtin_amdgcn_sinf(t0);
            v.y = __builtin_amdgcn_cosf(t0);
            v.z = __builtin_amdgcn_sinf(t1);
            v.w = __builtin_amdgcn_cosf(t1);
            *reinterpret_cast<float4*>(out + (size_t)(base + r) * DIM + lane * 4) = v;
        }
    }
}

extern "C" void kernel_launch(void* const* d_in, const int* in_sizes, int n_in,
                              void* d_out, int out_size, void* d_ws, size_t ws_size,
                              hipStream_t stream) {
    const float* x = (const float*)d_in[0];
    float* out = (float*)d_out;
    const int n = in_sizes[0];  // 1048576 rows

    const int block = 256;  // 4 waves/block
    const int grid = 256;   // 1024 waves: 1 block/CU, 1 MiB contiguous per wave
    SinusoidalEmbedding_kernel<<<grid, block, 0, stream>>>(x, out, n);
}

// Round 7
// 194.721 us; speedup vs baseline: 1.1528x; 1.0514x over previous
//
#include <hip/hip_runtime.h>

#define DIM 256

// 4096 blocks x 256 thr = 16384 waves (32 waves/CU, full occupancy).
// Each wave owns exactly ONE contiguous 64-row chunk (64 KiB of output):
//   - one coalesced x-load (lane l -> x[base+l]) up front, no mid-kernel loads
//   - 64 fully-unrolled rows; __shfl(xv, const) => v_readlane SGPR broadcast
//   - per row: 2 muls, 2 v_fract, 4 HW transcendentals, one dwordx4 store
//     (wave covers 1 KiB contiguous per store instruction)
// Experiment: stream-count axis in the favored direction (8192 -> 16384
// shorter streams), after 1024-long-streams / nt / sweep all regressed.
// v_sin/v_cos take REVOLUTIONS: freqs premultiplied by 1/(2pi).
__global__ __launch_bounds__(256) void SinusoidalEmbedding_kernel(
    const float* __restrict__ x, float* __restrict__ out, int n) {
    const int lane = threadIdx.x & 63;
    const int wid = blockIdx.x * (blockDim.x >> 6) + (threadIdx.x >> 6);
    const int nw = gridDim.x * (blockDim.x >> 6);  // 16384 waves

    const float k = 0.103810252965228506f;      // log2(10000)/128
    const float INV2PI = 0.15915494309189535f;  // radians -> revolutions
    const float i0f = (float)(2 * lane);
    const float g0 = exp2f(-i0f * k) * INV2PI;          // lane's freq 2j
    const float g1 = exp2f(-(i0f + 1.0f) * k) * INV2PI; // lane's freq 2j+1

    for (int base = wid << 6; base < n; base += nw << 6) {
        const int nb = min(64, n - base);
        const float xv = (lane < nb) ? x[base + lane] : 0.0f;  // 1 coalesced load
        float* o = out + (size_t)base * DIM + lane * 4;

        if (nb == 64) {
            #pragma unroll
            for (int r = 0; r < 64; ++r) {
                const float xr = __shfl(xv, r);  // v_readlane (const idx)
                const float t0 = __builtin_amdgcn_fractf(xr * g0);
                const float t1 = __builtin_amdgcn_fractf(xr * g1);
                float4 v;
                v.x = __builtin_amdgcn_sinf(t0);  // sin(2*pi*t)
                v.y = __builtin_amdgcn_cosf(t0);
                v.z = __builtin_amdgcn_sinf(t1);
                v.w = __builtin_amdgcn_cosf(t1);
                *reinterpret_cast<float4*>(o + (size_t)r * DIM) = v;
            }
        } else {
            for (int r = 0; r < nb; ++r) {  // tail — not hit at n = 1048576
                const float xr = __shfl(xv, r);
                const float t0 = __builtin_amdgcn_fractf(xr * g0);
                const float t1 = __builtin_amdgcn_fractf(xr * g1);
                float4 v;
                v.x = __builtin_amdgcn_sinf(t0);
                v.y = __builtin_amdgcn_cosf(t0);
                v.z = __builtin_amdgcn_sinf(t1);
                v.w = __builtin_amdgcn_cosf(t1);
                *reinterpret_cast<float4*>(o + (size_t)r * DIM) = v;
            }
        }
    }
}

extern "C" void kernel_launch(void* const* d_in, const int* in_sizes, int n_in,
                              void* d_out, int out_size, void* d_ws, size_t ws_size,
                              hipStream_t stream) {
    const float* x = (const float*)d_in[0];
    float* out = (float*)d_out;
    const int n = in_sizes[0];  // 1048576 rows

    const int block = 256;  // 4 waves/block
    const int grid = 4096;  // 16384 waves -> exactly one 64-row chunk each
    SinusoidalEmbedding_kernel<<<grid, block, 0, stream>>>(x, out, n);
}

// Round 8
// 194.158 us; speedup vs baseline: 1.1562x; 1.0029x over previous
//
#include <hip/hip_runtime.h>

#define DIM 256

// 4096 blocks x 256 thr = 16384 waves; each wave owns ONE contiguous 64-row
// (64 KiB) output chunk. NEW vs round 7: compute-then-burst store clustering.
// Per 8-row group: compute all 8 float4 results into registers (fully
// unrolled -> static indexing -> stays in VGPRs), THEN issue 8 back-to-back
// dwordx4 stores = 8 KiB uninterrupted store burst per wave (mimics
// fillBufferAligned's store train, testing whether store-burst density is
// what separates our 5.57 TB/s from fill's 6.6 TB/s).
// v_sin/v_cos take REVOLUTIONS: freqs premultiplied by 1/(2pi), v_fract reduce.
__global__ __launch_bounds__(256) void SinusoidalEmbedding_kernel(
    const float* __restrict__ x, float* __restrict__ out, int n) {
    const int lane = threadIdx.x & 63;
    const int wid = blockIdx.x * (blockDim.x >> 6) + (threadIdx.x >> 6);
    const int nw = gridDim.x * (blockDim.x >> 6);  // 16384 waves

    const float k = 0.103810252965228506f;      // log2(10000)/128
    const float INV2PI = 0.15915494309189535f;  // radians -> revolutions
    const float i0f = (float)(2 * lane);
    const float g0 = exp2f(-i0f * k) * INV2PI;          // lane's freq 2j
    const float g1 = exp2f(-(i0f + 1.0f) * k) * INV2PI; // lane's freq 2j+1

    for (int base = wid << 6; base < n; base += nw << 6) {
        const int nb = min(64, n - base);
        const float xv = (lane < nb) ? x[base + lane] : 0.0f;  // 1 coalesced load
        float* o = out + (size_t)base * DIM + lane * 4;

        if (nb == 64) {
            #pragma unroll
            for (int g = 0; g < 8; ++g) {
                float4 v[8];  // 32 VGPRs, static-indexed (full unroll)
                #pragma unroll
                for (int j = 0; j < 8; ++j) {
                    const float xr = __shfl(xv, g * 8 + j);  // v_readlane
                    const float t0 = __builtin_amdgcn_fractf(xr * g0);
                    const float t1 = __builtin_amdgcn_fractf(xr * g1);
                    v[j].x = __builtin_amdgcn_sinf(t0);  // sin(2*pi*t)
                    v[j].y = __builtin_amdgcn_cosf(t0);
                    v[j].z = __builtin_amdgcn_sinf(t1);
                    v[j].w = __builtin_amdgcn_cosf(t1);
                }
                #pragma unroll
                for (int j = 0; j < 8; ++j) {  // 8 KiB contiguous store burst
                    *reinterpret_cast<float4*>(o + (size_t)(g * 8 + j) * DIM) = v[j];
                }
            }
        } else {
            for (int r = 0; r < nb; ++r) {  // tail — not hit at n = 1048576
                const float xr = __shfl(xv, r);
                const float t0 = __builtin_amdgcn_fractf(xr * g0);
                const float t1 = __builtin_amdgcn_fractf(xr * g1);
                float4 v;
                v.x = __builtin_amdgcn_sinf(t0);
                v.y = __builtin_amdgcn_cosf(t0);
                v.z = __builtin_amdgcn_sinf(t1);
                v.w = __builtin_amdgcn_cosf(t1);
                *reinterpret_cast<float4*>(o + (size_t)r * DIM) = v;
            }
        }
    }
}

extern "C" void kernel_launch(void* const* d_in, const int* in_sizes, int n_in,
                              void* d_out, int out_size, void* d_ws, size_t ws_size,
                              hipStream_t stream) {
    const float* x = (const float*)d_in[0];
    float* out = (float*)d_out;
    const int n = in_sizes[0];  // 1048576 rows

    const int block = 256;  // 4 waves/block
    const int grid = 4096;  // 16384 waves -> exactly one 64-row chunk each
    SinusoidalEmbedding_kernel<<<grid, block, 0, stream>>>(x, out, n);
}